// Round 1
// baseline (398.285 us; speedup 1.0000x reference)
//
#include <hip/hip_runtime.h>
#include <hip/hip_bf16.h>
#include <stdint.h>

#define NROWS 8192
#define DDIM  256
#define SIGMA_INV 10.0f

#define BM 64
#define BN 64
#define NSPLIT 6                  // grid = 128*6 = 768 = exactly 3 blocks/CU
#define NTILES (NROWS / BN)       // 128 j-tiles of 64 rows
#define PSTR   72                 // pl row stride in halfs (144B, 16B-aligned)
#define KCHB   1056               // DMA chunk pitch: 1024B payload + 32B pad -> conflict-free reads

typedef __attribute__((ext_vector_type(8))) short bf16x8;
typedef __attribute__((ext_vector_type(4))) float f32x4;

__device__ inline unsigned short f2bf(float x) {
  __hip_bfloat16 h = __float2bfloat16(x);
  return *reinterpret_cast<unsigned short*>(&h);
}

__device__ inline void dma16(const void* g, void* l) {
  __builtin_amdgcn_global_load_lds(
      (const __attribute__((address_space(1))) unsigned int*)g,
      (__attribute__((address_space(3))) unsigned int*)l, 16, 0, 0);
}

// ---------------- K0: L2-normalize rows -> bf16 ----------------
__global__ __launch_bounds__(256) void normalize_k(const float* __restrict__ emb,
                                                   unsigned short* __restrict__ embn) {
  const int w = threadIdx.x >> 6, lane = threadIdx.x & 63;
  const int row = blockIdx.x * 4 + w;
  const float4* src = (const float4*)(emb + (size_t)row * DDIM);
  float4 v = src[lane];
  float ss = v.x * v.x + v.y * v.y + v.z * v.z + v.w * v.w;
  for (int off = 32; off >= 1; off >>= 1) ss += __shfl_xor(ss, off);
  const float sc = 1.0f / fmaxf(sqrtf(ss), 1e-12f);
  ushort4 o;
  o.x = f2bf(v.x * sc); o.y = f2bf(v.y * sc);
  o.z = f2bf(v.z * sc); o.w = f2bf(v.w * sc);
  ((ushort4*)(embn + (size_t)row * DDIM))[lane] = o;
}

// ---------------- K0b: emb[N][D] fp32 -> vt TILED bf16 ----------------
// vt layout: [jtile = j/64][d = 0..255][jj = j%64]  (32KB contiguous per j-tile)
// -> fused_k's per-iter V reads hit one contiguous 32KB block instead of
//    64B segments at 16KB stride (L2-channel / L1 pathology).
__global__ __launch_bounds__(256) void transpose_k(const float* __restrict__ emb,
                                                   unsigned short* __restrict__ vt) {
  __shared__ float tile[64][65];
  const int r0 = blockIdx.x * 64, c0 = blockIdx.y * 64;
  const int tr = threadIdx.x >> 6, tc = threadIdx.x & 63;
  for (int i = 0; i < 16; ++i)
    tile[i * 4 + tr][tc] = emb[(size_t)(r0 + i * 4 + tr) * DDIM + c0 + tc];
  __syncthreads();
  unsigned short* dst = vt + (size_t)(r0 >> 6) * (DDIM * BN);   // jtile = r0/64
  for (int i = 0; i < 16; ++i)
    dst[(size_t)(c0 + i * 4 + tr) * BN + tc] = f2bf(tile[tc][i * 4 + tr]);
}

// ---------------- F: fused  S=Qn.Knt -> exp -> O += P.V, row sums ----------------
// grid = 128 mblk x 6 chunks = 768 blocks = exactly 3 blocks/CU (12 waves/CU),
// 256 threads. launch_bounds(256,3) caps VGPR at ~168 to protect occupancy.
// Schedule per iter (2 barriers):
//   B1 (__syncthreads: vmcnt(0) drains DMA(t), issued a full G2 earlier)
//   G1: S = Q.Kn^T from padded-pitch kn (conflict-free b128 reads)
//   vfrag(t) issue [16 vmem]           <- consumed in G2 via counted vmcnt
//   exp -> pl (bf16 transit)
//   B2 RAW: lgkmcnt(0) + s_barrier     <- NO vmcnt drain: vfrag+DMA ride through
//   DMA(t+1) issue [8 vmem]            <- legal after B2 (all kn reads retired);
//                                         cover to next B1 = whole G2
//   G2: O += P.V   (vfrag waits resolve at vmcnt<=8, DMA stays in flight)
__global__ __launch_bounds__(256, 3) void fused_k(
    const unsigned short* __restrict__ embn,  // [N][D] bf16 normalized
    const unsigned short* __restrict__ vt,    // tiled [N/64][256][64] bf16
    float* __restrict__ out,                  // [N][D] fp32, pre-zeroed, atomic accum
    float* __restrict__ l_part)               // [N] fp32, pre-zeroed, atomic accum
{
  __shared__ char kn[32 * KCHB];              // 33 KB, padded DMA-staged K-tile
  __shared__ unsigned short pl[BM * PSTR];    // 9 KB, P transit

  const int tid = threadIdx.x;
  const int w = tid >> 6, lane = tid & 63;
  const int mg = w >> 1, dh = w & 1;          // m-group, d-half
  const int q = lane >> 4, c = lane & 15;
  const int chunk = blockIdx.x % NSPLIT;
  const int mblk = blockIdx.x / NSPLIT;
  const int row0 = mblk * BM + mg * 32;
  const int t0 = (chunk * NTILES) / NSPLIT;        // chunk j-tile range (21 or 22 tiles)
  const int t1 = ((chunk + 1) * NTILES) / NSPLIT;

  // Q fragments resident: A[m=lane&15][k=q*8+j]
  bf16x8 qa[2][8];
  for (int mt = 0; mt < 2; ++mt)
    for (int k = 0; k < 8; ++k)
      qa[mt][k] = *(const bf16x8*)(embn + (size_t)(row0 + mt * 16 + c) * DDIM + k * 32 + q * 8);

  f32x4 oacc[2][8];
  for (int mt = 0; mt < 2; ++mt)
    for (int u = 0; u < 8; ++u) oacc[mt][u] = {0.f, 0.f, 0.f, 0.f};
  float lacc[2][4] = {};

  // prologue: stage first K-tile (32 x 1KB chunks at 1056B pitch, 8 per wave)
  {
    const char* src = (const char*)(embn + (size_t)t0 * BN * DDIM);
    for (int cc = 0; cc < 8; ++cc) {
      const int ch = w * 8 + cc;
      dma16(src + ch * 1024 + lane * 16, kn + ch * KCHB + lane * 16);
    }
  }

  // kn row r (512B payload) lives at (r>>1)*KCHB + (r&1)*512
  for (int it = t0; it < t1; ++it) {
    __syncthreads();  // B1: DMA(it) drained (vmcnt(0)); pl reads of iter it-1 drained

    // ---- G1: S[32x64] = Q . Kn^T (kn reads conflict-free via padded pitch) ----
    f32x4 sacc[2][2];
    for (int mt = 0; mt < 2; ++mt)
      for (int nt = 0; nt < 2; ++nt) sacc[mt][nt] = {0.f, 0.f, 0.f, 0.f};
    const int rb0 = (dh * 16 + (c >> 1)) * KCHB + (c & 1) * 512;        // row dh*32+c
    const int rb1 = (dh * 16 + 8 + (c >> 1)) * KCHB + (c & 1) * 512;    // row dh*32+16+c
    for (int k = 0; k < 8; ++k) {
      bf16x8 b0 = *(const bf16x8*)(kn + rb0 + k * 64 + q * 16);
      bf16x8 b1 = *(const bf16x8*)(kn + rb1 + k * 64 + q * 16);
      for (int mt = 0; mt < 2; ++mt) {
        sacc[mt][0] = __builtin_amdgcn_mfma_f32_16x16x32_bf16(qa[mt][k], b0, sacc[mt][0], 0, 0, 0);
        sacc[mt][1] = __builtin_amdgcn_mfma_f32_16x16x32_bf16(qa[mt][k], b1, sacc[mt][1], 0, 0, 0);
      }
    }

    // prefetch V frags into registers from the CONTIGUOUS 32KB j-tile.
    // Issued before the DMA below -> in-order vmcnt retirement lets G2 consume
    // them at vmcnt<=8 while the 8 DMA loads stay in flight.
    const unsigned short* vtile = vt + (size_t)it * (DDIM * BN);
    bf16x8 vfrag[2][8];
    for (int kk = 0; kk < 2; ++kk)
      for (int u = 0; u < 8; ++u)
        vfrag[kk][u] = *(const bf16x8*)(vtile + (size_t)(dh * 128 + u * 16 + c) * BN + kk * 32 + q * 8);

    // exp (fixed shift 10; cos<=1 so logits<=10, softmax shift-invariant) + P + row sums
    for (int mt = 0; mt < 2; ++mt)
      for (int nt = 0; nt < 2; ++nt)
        for (int r = 0; r < 4; ++r) {
          const float p = __expf(fmaf(SIGMA_INV, sacc[mt][nt][r], -SIGMA_INV));
          lacc[mt][r] += p;
          // C/D layout: row = q*4+r, col = c
          pl[(mg * 32 + mt * 16 + q * 4 + r) * PSTR + dh * 32 + nt * 16 + c] = f2bf(p);
        }

    // B2 RAW barrier: pl writes + kn ds_reads retired (lgkmcnt only).
    // Deliberately NO vmcnt drain — vfrag loads stay outstanding.
    __builtin_amdgcn_sched_barrier(0);
    asm volatile("s_waitcnt lgkmcnt(0)" ::: "memory");
    __builtin_amdgcn_sched_barrier(0);
    __builtin_amdgcn_s_barrier();
    __builtin_amdgcn_sched_barrier(0);

    // stage NEXT K-tile now: all waves' kn reads retired at B2; overlaps the
    // whole of G2 before the next B1's vmcnt(0) drain.
    if (it + 1 < t1) {
      const char* src = (const char*)(embn + (size_t)(it + 1) * BN * DDIM);
      for (int cc = 0; cc < 8; ++cc) {
        const int ch = w * 8 + cc;
        dma16(src + ch * 1024 + lane * 16, kn + ch * KCHB + lane * 16);
      }
    }

    // ---- G2: O[32x128] += P[32x64] . V[64x128] ----
    for (int kk = 0; kk < 2; ++kk) {
      bf16x8 ap0 = *(const bf16x8*)(pl + (mg * 32 + c) * PSTR + kk * 32 + q * 8);
      bf16x8 ap1 = *(const bf16x8*)(pl + (mg * 32 + 16 + c) * PSTR + kk * 32 + q * 8);
      for (int u = 0; u < 8; ++u) {
        oacc[0][u] = __builtin_amdgcn_mfma_f32_16x16x32_bf16(ap0, vfrag[kk][u], oacc[0][u], 0, 0, 0);
        oacc[1][u] = __builtin_amdgcn_mfma_f32_16x16x32_bf16(ap1, vfrag[kk][u], oacc[1][u], 0, 0, 0);
      }
    }
  }

  // epilogue: row sums across the 16 c-lanes, then device atomics
  for (int mt = 0; mt < 2; ++mt)
    for (int r = 0; r < 4; ++r) {
      float s = lacc[mt][r];
      s += __shfl_xor(s, 1); s += __shfl_xor(s, 2);
      s += __shfl_xor(s, 4); s += __shfl_xor(s, 8);
      if (c == 0)
        atomicAdd(&l_part[row0 + mt * 16 + q * 4 + r], s);
    }
  for (int mt = 0; mt < 2; ++mt)
    for (int u = 0; u < 8; ++u)
      for (int r = 0; r < 4; ++r)
        atomicAdd(&out[(size_t)(row0 + mt * 16 + q * 4 + r) * DDIM + dh * 128 + u * 16 + c],
                  oacc[mt][u][r]);
}

// ---------------- K4: divide by row sums ----------------
__global__ __launch_bounds__(256) void finalize_k(float* __restrict__ out,
                                                  const float* __restrict__ l_part) {
  const int row = blockIdx.x, t = threadIdx.x;
  out[(size_t)row * DDIM + t] /= l_part[row];
}

extern "C" void kernel_launch(void* const* d_in, const int* in_sizes, int n_in,
                              void* d_out, int out_size, void* d_ws, size_t ws_size,
                              hipStream_t stream) {
  const float* emb = (const float*)d_in[0];
  float* out = (float*)d_out;
  char* ws = (char*)d_ws;
  // ws layout: embn 4MB | vt 4MB | l_part 32KB
  unsigned short* embn = (unsigned short*)ws;
  unsigned short* vt   = (unsigned short*)(ws + ((size_t)4 << 20));
  float* l_part        = (float*)(ws + ((size_t)8 << 20));

  hipMemsetAsync(out, 0, (size_t)NROWS * DDIM * sizeof(float), stream);
  hipMemsetAsync(l_part, 0, (size_t)NROWS * sizeof(float), stream);

  normalize_k<<<NROWS / 4, 256, 0, stream>>>(emb, embn);
  transpose_k<<<dim3(NROWS / 64, DDIM / 64), 256, 0, stream>>>(emb, vt);
  fused_k<<<(NROWS / BM) * NSPLIT, 256, 0, stream>>>(embn, vt, out, l_part);
  finalize_k<<<NROWS, 256, 0, stream>>>(out, l_part);
}

// Round 2
// 256.408 us; speedup vs baseline: 1.5533x; 1.5533x over previous
//
#include <hip/hip_runtime.h>
#include <hip/hip_bf16.h>
#include <stdint.h>

#define NROWS 8192
#define DDIM  256
#define SIGMA_INV 10.0f

#define BM 64
#define BN 64
#define NSPLIT 6                  // grid = 128*6 = 768 = exactly 3 blocks/CU
#define NTILES (NROWS / BN)       // 128 j-tiles of 64 rows
#define PSTR   72                 // pl row stride in halfs (144B, 16B-aligned)
#define KCHB   1056               // DMA chunk pitch: 1024B payload + 32B pad -> conflict-free reads

typedef __attribute__((ext_vector_type(8))) short bf16x8;
typedef __attribute__((ext_vector_type(4))) float f32x4;

__device__ inline unsigned short f2bf(float x) {
  __hip_bfloat16 h = __float2bfloat16(x);
  return *reinterpret_cast<unsigned short*>(&h);
}

__device__ inline void dma16(const void* g, void* l) {
  __builtin_amdgcn_global_load_lds(
      (const __attribute__((address_space(1))) unsigned int*)g,
      (__attribute__((address_space(3))) unsigned int*)l, 16, 0, 0);
}

// ---------------- K0: L2-normalize rows -> bf16 ----------------
__global__ __launch_bounds__(256) void normalize_k(const float* __restrict__ emb,
                                                   unsigned short* __restrict__ embn) {
  const int w = threadIdx.x >> 6, lane = threadIdx.x & 63;
  const int row = blockIdx.x * 4 + w;
  const float4* src = (const float4*)(emb + (size_t)row * DDIM);
  float4 v = src[lane];
  float ss = v.x * v.x + v.y * v.y + v.z * v.z + v.w * v.w;
  for (int off = 32; off >= 1; off >>= 1) ss += __shfl_xor(ss, off);
  const float sc = 1.0f / fmaxf(sqrtf(ss), 1e-12f);
  ushort4 o;
  o.x = f2bf(v.x * sc); o.y = f2bf(v.y * sc);
  o.z = f2bf(v.z * sc); o.w = f2bf(v.w * sc);
  ((ushort4*)(embn + (size_t)row * DDIM))[lane] = o;
}

// ---------------- K0b: emb[N][D] fp32 -> vt TILED bf16 ----------------
// vt layout: [jtile = j/64][d = 0..255][jj = j%64]  (32KB contiguous per j-tile)
// -> fused_k's per-iter V reads hit one contiguous 32KB block instead of
//    64B segments at 16KB stride (L2-channel / L1 pathology).
__global__ __launch_bounds__(256) void transpose_k(const float* __restrict__ emb,
                                                   unsigned short* __restrict__ vt) {
  __shared__ float tile[64][65];
  const int r0 = blockIdx.x * 64, c0 = blockIdx.y * 64;
  const int tr = threadIdx.x >> 6, tc = threadIdx.x & 63;
  for (int i = 0; i < 16; ++i)
    tile[i * 4 + tr][tc] = emb[(size_t)(r0 + i * 4 + tr) * DDIM + c0 + tc];
  __syncthreads();
  unsigned short* dst = vt + (size_t)(r0 >> 6) * (DDIM * BN);   // jtile = r0/64
  for (int i = 0; i < 16; ++i)
    dst[(size_t)(c0 + i * 4 + tr) * BN + tc] = f2bf(tile[tc][i * 4 + tr]);
}

// ---------------- F: fused  S=Qn.Knt -> exp -> O += P.V, row sums ----------------
// grid = 128 mblk x 6 chunks = 768 blocks = exactly 3 blocks/CU (12 waves/CU),
// 256 threads.
// NOTE: launch_bounds 2nd arg MUST stay 2. (256,3) made the allocator target
// ~6 waves/SIMD -> 84 VGPR -> spills of qa/vfrag/oacc to scratch -> 649MB
// FETCH/dispatch, 2x slower (round-1 regression). At (256,2) codegen is
// 128 VGPR / no spill, and 3 blocks/CU still fit (3*128 <= 512 VGPR slots,
// 3*43KB <= 160KB LDS) -- hardware schedules 3/CU regardless of the hint.
// Schedule per iter (2 barriers):
//   B1 (__syncthreads: vmcnt(0) drains DMA(t), issued a full G2 earlier)
//   G1: S = Q.Kn^T from padded-pitch kn (conflict-free b128 reads)
//   vfrag(t) issue [16 vmem]           <- consumed in G2 via counted vmcnt
//   exp -> pl (bf16 transit)
//   B2 RAW: lgkmcnt(0) + s_barrier     <- NO vmcnt drain: vfrag+DMA ride through
//   DMA(t+1) issue [8 vmem]            <- legal after B2 (all kn reads retired);
//                                         cover to next B1 = whole G2
//   G2: O += P.V   (vfrag waits resolve at vmcnt<=8, DMA stays in flight)
__global__ __launch_bounds__(256, 2) void fused_k(
    const unsigned short* __restrict__ embn,  // [N][D] bf16 normalized
    const unsigned short* __restrict__ vt,    // tiled [N/64][256][64] bf16
    float* __restrict__ out,                  // [N][D] fp32, pre-zeroed, atomic accum
    float* __restrict__ l_part)               // [N] fp32, pre-zeroed, atomic accum
{
  __shared__ char kn[32 * KCHB];              // 33 KB, padded DMA-staged K-tile
  __shared__ unsigned short pl[BM * PSTR];    // 9 KB, P transit

  const int tid = threadIdx.x;
  const int w = tid >> 6, lane = tid & 63;
  const int mg = w >> 1, dh = w & 1;          // m-group, d-half
  const int q = lane >> 4, c = lane & 15;
  const int chunk = blockIdx.x % NSPLIT;
  const int mblk = blockIdx.x / NSPLIT;
  const int row0 = mblk * BM + mg * 32;
  const int t0 = (chunk * NTILES) / NSPLIT;        // chunk j-tile range (21 or 22 tiles)
  const int t1 = ((chunk + 1) * NTILES) / NSPLIT;

  // Q fragments resident: A[m=lane&15][k=q*8+j]
  bf16x8 qa[2][8];
  for (int mt = 0; mt < 2; ++mt)
    for (int k = 0; k < 8; ++k)
      qa[mt][k] = *(const bf16x8*)(embn + (size_t)(row0 + mt * 16 + c) * DDIM + k * 32 + q * 8);

  f32x4 oacc[2][8];
  for (int mt = 0; mt < 2; ++mt)
    for (int u = 0; u < 8; ++u) oacc[mt][u] = {0.f, 0.f, 0.f, 0.f};
  float lacc[2][4] = {};

  // prologue: stage first K-tile (32 x 1KB chunks at 1056B pitch, 8 per wave)
  {
    const char* src = (const char*)(embn + (size_t)t0 * BN * DDIM);
    for (int cc = 0; cc < 8; ++cc) {
      const int ch = w * 8 + cc;
      dma16(src + ch * 1024 + lane * 16, kn + ch * KCHB + lane * 16);
    }
  }

  // kn row r (512B payload) lives at (r>>1)*KCHB + (r&1)*512
  for (int it = t0; it < t1; ++it) {
    __syncthreads();  // B1: DMA(it) drained (vmcnt(0)); pl reads of iter it-1 drained

    // ---- G1: S[32x64] = Q . Kn^T (kn reads conflict-free via padded pitch) ----
    f32x4 sacc[2][2];
    for (int mt = 0; mt < 2; ++mt)
      for (int nt = 0; nt < 2; ++nt) sacc[mt][nt] = {0.f, 0.f, 0.f, 0.f};
    const int rb0 = (dh * 16 + (c >> 1)) * KCHB + (c & 1) * 512;        // row dh*32+c
    const int rb1 = (dh * 16 + 8 + (c >> 1)) * KCHB + (c & 1) * 512;    // row dh*32+16+c
    for (int k = 0; k < 8; ++k) {
      bf16x8 b0 = *(const bf16x8*)(kn + rb0 + k * 64 + q * 16);
      bf16x8 b1 = *(const bf16x8*)(kn + rb1 + k * 64 + q * 16);
      for (int mt = 0; mt < 2; ++mt) {
        sacc[mt][0] = __builtin_amdgcn_mfma_f32_16x16x32_bf16(qa[mt][k], b0, sacc[mt][0], 0, 0, 0);
        sacc[mt][1] = __builtin_amdgcn_mfma_f32_16x16x32_bf16(qa[mt][k], b1, sacc[mt][1], 0, 0, 0);
      }
    }

    // prefetch V frags into registers from the CONTIGUOUS 32KB j-tile.
    // Issued before the DMA below -> in-order vmcnt retirement lets G2 consume
    // them at vmcnt<=8 while the 8 DMA loads stay in flight.
    const unsigned short* vtile = vt + (size_t)it * (DDIM * BN);
    bf16x8 vfrag[2][8];
    for (int kk = 0; kk < 2; ++kk)
      for (int u = 0; u < 8; ++u)
        vfrag[kk][u] = *(const bf16x8*)(vtile + (size_t)(dh * 128 + u * 16 + c) * BN + kk * 32 + q * 8);

    // exp (fixed shift 10; cos<=1 so logits<=10, softmax shift-invariant) + P + row sums
    for (int mt = 0; mt < 2; ++mt)
      for (int nt = 0; nt < 2; ++nt)
        for (int r = 0; r < 4; ++r) {
          const float p = __expf(fmaf(SIGMA_INV, sacc[mt][nt][r], -SIGMA_INV));
          lacc[mt][r] += p;
          // C/D layout: row = q*4+r, col = c
          pl[(mg * 32 + mt * 16 + q * 4 + r) * PSTR + dh * 32 + nt * 16 + c] = f2bf(p);
        }

    // B2 RAW barrier: pl writes + kn ds_reads retired (lgkmcnt only).
    // Deliberately NO vmcnt drain — vfrag loads stay outstanding.
    __builtin_amdgcn_sched_barrier(0);
    asm volatile("s_waitcnt lgkmcnt(0)" ::: "memory");
    __builtin_amdgcn_sched_barrier(0);
    __builtin_amdgcn_s_barrier();
    __builtin_amdgcn_sched_barrier(0);

    // stage NEXT K-tile now: all waves' kn reads retired at B2; overlaps the
    // whole of G2 before the next B1's vmcnt(0) drain.
    if (it + 1 < t1) {
      const char* src = (const char*)(embn + (size_t)(it + 1) * BN * DDIM);
      for (int cc = 0; cc < 8; ++cc) {
        const int ch = w * 8 + cc;
        dma16(src + ch * 1024 + lane * 16, kn + ch * KCHB + lane * 16);
      }
    }

    // ---- G2: O[32x128] += P[32x64] . V[64x128] ----
    for (int kk = 0; kk < 2; ++kk) {
      bf16x8 ap0 = *(const bf16x8*)(pl + (mg * 32 + c) * PSTR + kk * 32 + q * 8);
      bf16x8 ap1 = *(const bf16x8*)(pl + (mg * 32 + 16 + c) * PSTR + kk * 32 + q * 8);
      for (int u = 0; u < 8; ++u) {
        oacc[0][u] = __builtin_amdgcn_mfma_f32_16x16x32_bf16(ap0, vfrag[kk][u], oacc[0][u], 0, 0, 0);
        oacc[1][u] = __builtin_amdgcn_mfma_f32_16x16x32_bf16(ap1, vfrag[kk][u], oacc[1][u], 0, 0, 0);
      }
    }
  }

  // epilogue: row sums across the 16 c-lanes, then device atomics
  for (int mt = 0; mt < 2; ++mt)
    for (int r = 0; r < 4; ++r) {
      float s = lacc[mt][r];
      s += __shfl_xor(s, 1); s += __shfl_xor(s, 2);
      s += __shfl_xor(s, 4); s += __shfl_xor(s, 8);
      if (c == 0)
        atomicAdd(&l_part[row0 + mt * 16 + q * 4 + r], s);
    }
  for (int mt = 0; mt < 2; ++mt)
    for (int u = 0; u < 8; ++u)
      for (int r = 0; r < 4; ++r)
        atomicAdd(&out[(size_t)(row0 + mt * 16 + q * 4 + r) * DDIM + dh * 128 + u * 16 + c],
                  oacc[mt][u][r]);
}

// ---------------- K4: divide by row sums ----------------
__global__ __launch_bounds__(256) void finalize_k(float* __restrict__ out,
                                                  const float* __restrict__ l_part) {
  const int row = blockIdx.x, t = threadIdx.x;
  out[(size_t)row * DDIM + t] /= l_part[row];
}

extern "C" void kernel_launch(void* const* d_in, const int* in_sizes, int n_in,
                              void* d_out, int out_size, void* d_ws, size_t ws_size,
                              hipStream_t stream) {
  const float* emb = (const float*)d_in[0];
  float* out = (float*)d_out;
  char* ws = (char*)d_ws;
  // ws layout: embn 4MB | vt 4MB | l_part 32KB
  unsigned short* embn = (unsigned short*)ws;
  unsigned short* vt   = (unsigned short*)(ws + ((size_t)4 << 20));
  float* l_part        = (float*)(ws + ((size_t)8 << 20));

  hipMemsetAsync(out, 0, (size_t)NROWS * DDIM * sizeof(float), stream);
  hipMemsetAsync(l_part, 0, (size_t)NROWS * sizeof(float), stream);

  normalize_k<<<NROWS / 4, 256, 0, stream>>>(emb, embn);
  transpose_k<<<dim3(NROWS / 64, DDIM / 64), 256, 0, stream>>>(emb, vt);
  fused_k<<<(NROWS / BM) * NSPLIT, 256, 0, stream>>>(embn, vt, out, l_part);
  finalize_k<<<NROWS, 256, 0, stream>>>(out, l_part);
}

// Round 3
// 243.116 us; speedup vs baseline: 1.6382x; 1.0547x over previous
//
#include <hip/hip_runtime.h>
#include <hip/hip_bf16.h>
#include <stdint.h>

#define NROWS 8192
#define DDIM  256
#define SIGMA_INV 10.0f

#define BM 64
#define BN 64
#define NSPLIT 4                  // MUST divide 8: chunk=b%4, XCD=b%8 -> each XCD
                                  // serves ONE 2MB j-slice (L2-resident). NSPLIT=6
                                  // broke this (lcm 24 -> 3 chunks/XCD, 6MB > 4MB L2,
                                  // FETCH 14->31MB) AND gave 1.5 dispatch rounds at
                                  // the real 2-block/CU residency. Round-2 lesson.
#define JCHUNK (NROWS / NSPLIT)   // 2048
#define NITER  (JCHUNK / BN)      // 32
#define PSTR   72                 // pl row stride in halfs (144B, 16B-aligned)
#define KCHB   1056               // DMA chunk pitch: 1024B payload + 32B pad -> conflict-free reads
#define KNSZ   (32 * KCHB)        // one K-tile buffer: 33792 B

typedef __attribute__((ext_vector_type(8))) short bf16x8;
typedef __attribute__((ext_vector_type(4))) float f32x4;

__device__ inline unsigned short f2bf(float x) {
  __hip_bfloat16 h = __float2bfloat16(x);
  return *reinterpret_cast<unsigned short*>(&h);
}

__device__ inline void dma16(const void* g, void* l) {
  __builtin_amdgcn_global_load_lds(
      (const __attribute__((address_space(1))) unsigned int*)g,
      (__attribute__((address_space(3))) unsigned int*)l, 16, 0, 0);
}

// ---------------- K0: L2-normalize rows -> bf16 ----------------
__global__ __launch_bounds__(256) void normalize_k(const float* __restrict__ emb,
                                                   unsigned short* __restrict__ embn) {
  const int w = threadIdx.x >> 6, lane = threadIdx.x & 63;
  const int row = blockIdx.x * 4 + w;
  const float4* src = (const float4*)(emb + (size_t)row * DDIM);
  float4 v = src[lane];
  float ss = v.x * v.x + v.y * v.y + v.z * v.z + v.w * v.w;
  for (int off = 32; off >= 1; off >>= 1) ss += __shfl_xor(ss, off);
  const float sc = 1.0f / fmaxf(sqrtf(ss), 1e-12f);
  ushort4 o;
  o.x = f2bf(v.x * sc); o.y = f2bf(v.y * sc);
  o.z = f2bf(v.z * sc); o.w = f2bf(v.w * sc);
  ((ushort4*)(embn + (size_t)row * DDIM))[lane] = o;
}

// ---------------- K0b: emb[N][D] fp32 -> vt TILED bf16 ----------------
// vt layout: [jtile = j/64][d = 0..255][jj = j%64]  (32KB contiguous per j-tile)
__global__ __launch_bounds__(256) void transpose_k(const float* __restrict__ emb,
                                                   unsigned short* __restrict__ vt) {
  __shared__ float tile[64][65];
  const int r0 = blockIdx.x * 64, c0 = blockIdx.y * 64;
  const int tr = threadIdx.x >> 6, tc = threadIdx.x & 63;
  for (int i = 0; i < 16; ++i)
    tile[i * 4 + tr][tc] = emb[(size_t)(r0 + i * 4 + tr) * DDIM + c0 + tc];
  __syncthreads();
  unsigned short* dst = vt + (size_t)(r0 >> 6) * (DDIM * BN);   // jtile = r0/64
  for (int i = 0; i < 16; ++i)
    dst[(size_t)(c0 + i * 4 + tr) * BN + tc] = f2bf(tile[tc][i * 4 + tr]);
}

// ---------------- F: fused  S=Qn.Knt -> exp -> O += P.V, row sums ----------------
// grid = 128 mblk x 4 chunks = 512 blocks = exactly 2/CU (the real residency:
// ~124 arch VGPR + 64 acc regs ~= 192/wave -> 2 waves/SIMD; round-1/2 evidence).
// kn is now DOUBLE-BUFFERED (2 x 33KB): DMA(t+1) issues at the TOP of iter t
// (buffer freed at t-1's B2), so the next B1 vmcnt(0) drain has a FULL
// ITERATION of cover -> B1 DMA stall ~0. LDS 75KB/block, 2x75=150 <= 160KB.
// Schedule per iter:
//   B1 __syncthreads: DMA(t) drained (full-iter cover), pl reads of t-1 drained
//   DMA(t+1) -> kn[b^1]                 (8 vmem; covered by whole iter t)
//   G1: S = Q.Kn^T from kn[b]           (conflict-free padded-pitch b128 reads)
//   vfrag(t) issue [16 vmem]            (consumed in G2 via counted vmcnt;
//                                        in-order retire also completes DMA(t+1)
//                                        first -- it has G1+exp+B2 of cover)
//   exp -> pl
//   B2 RAW: lgkmcnt(0)+s_barrier        (no vmem drain; vfrag+DMA ride through)
//   G2: O += P.V
__global__ __launch_bounds__(256, 2) void fused_k(
    const unsigned short* __restrict__ embn,  // [N][D] bf16 normalized
    const unsigned short* __restrict__ vt,    // tiled [N/64][256][64] bf16
    float* __restrict__ out,                  // [N][D] fp32, pre-zeroed, atomic accum
    float* __restrict__ l_part)               // [N] fp32, pre-zeroed, atomic accum
{
  __shared__ char kn[2 * KNSZ];               // 66 KB, double-buffered DMA K-tiles
  __shared__ unsigned short pl[BM * PSTR];    // 9 KB, P transit

  const int tid = threadIdx.x;
  const int w = tid >> 6, lane = tid & 63;
  const int mg = w >> 1, dh = w & 1;          // m-group, d-half
  const int q = lane >> 4, c = lane & 15;
  const int chunk = blockIdx.x & 3;
  const int mblk = blockIdx.x >> 2;
  const int row0 = mblk * BM + mg * 32;
  const int t0 = chunk * NITER;               // j-tile range [t0, t1)
  const int t1 = t0 + NITER;

  // Q fragments resident: A[m=lane&15][k=q*8+j]
  bf16x8 qa[2][8];
  for (int mt = 0; mt < 2; ++mt)
    for (int k = 0; k < 8; ++k)
      qa[mt][k] = *(const bf16x8*)(embn + (size_t)(row0 + mt * 16 + c) * DDIM + k * 32 + q * 8);

  f32x4 oacc[2][8];
  for (int mt = 0; mt < 2; ++mt)
    for (int u = 0; u < 8; ++u) oacc[mt][u] = {0.f, 0.f, 0.f, 0.f};
  float lacc[2][4] = {};

  // prologue: stage first K-tile into kn[0] (32 x 1KB chunks at 1056B pitch, 8/wave)
  {
    const char* src = (const char*)(embn + (size_t)t0 * BN * DDIM);
    for (int cc = 0; cc < 8; ++cc) {
      const int ch = w * 8 + cc;
      dma16(src + ch * 1024 + lane * 16, kn + ch * KCHB + lane * 16);
    }
  }

  // kn row r (512B payload) lives at bsel*KNSZ + (r>>1)*KCHB + (r&1)*512
  for (int it = t0; it < t1; ++it) {
    const int bsel = (it - t0) & 1;
    const char* knb = kn + bsel * KNSZ;

    __syncthreads();  // B1: vmcnt(0)+lgkmcnt(0)+barrier. DMA(it) (issued top of
                      // iter it-1 / prologue) drained with full-iter cover;
                      // pl reads of iter it-1 drained.

    // stage NEXT K-tile into the other buffer NOW: its readers (G1 of it-1)
    // retired at it-1's B2; covered by the entirety of iter it.
    if (it + 1 < t1) {
      const char* src = (const char*)(embn + (size_t)(it + 1) * BN * DDIM);
      char* dst = kn + (bsel ^ 1) * KNSZ;
      for (int cc = 0; cc < 8; ++cc) {
        const int ch = w * 8 + cc;
        dma16(src + ch * 1024 + lane * 16, dst + ch * KCHB + lane * 16);
      }
    }

    // ---- G1: S[32x64] = Q . Kn^T (kn reads conflict-free via padded pitch) ----
    f32x4 sacc[2][2];
    for (int mt = 0; mt < 2; ++mt)
      for (int nt = 0; nt < 2; ++nt) sacc[mt][nt] = {0.f, 0.f, 0.f, 0.f};
    const int rb0 = (dh * 16 + (c >> 1)) * KCHB + (c & 1) * 512;        // row dh*32+c
    const int rb1 = (dh * 16 + 8 + (c >> 1)) * KCHB + (c & 1) * 512;    // row dh*32+16+c
    for (int k = 0; k < 8; ++k) {
      bf16x8 b0 = *(const bf16x8*)(knb + rb0 + k * 64 + q * 16);
      bf16x8 b1 = *(const bf16x8*)(knb + rb1 + k * 64 + q * 16);
      for (int mt = 0; mt < 2; ++mt) {
        sacc[mt][0] = __builtin_amdgcn_mfma_f32_16x16x32_bf16(qa[mt][k], b0, sacc[mt][0], 0, 0, 0);
        sacc[mt][1] = __builtin_amdgcn_mfma_f32_16x16x32_bf16(qa[mt][k], b1, sacc[mt][1], 0, 0, 0);
      }
    }

    // prefetch V frags into registers from the CONTIGUOUS 32KB j-tile.
    const unsigned short* vtile = vt + (size_t)it * (DDIM * BN);
    bf16x8 vfrag[2][8];
    for (int kk = 0; kk < 2; ++kk)
      for (int u = 0; u < 8; ++u)
        vfrag[kk][u] = *(const bf16x8*)(vtile + (size_t)(dh * 128 + u * 16 + c) * BN + kk * 32 + q * 8);

    // exp (fixed shift 10; cos<=1 so logits<=10, softmax shift-invariant) + P + row sums
    for (int mt = 0; mt < 2; ++mt)
      for (int nt = 0; nt < 2; ++nt)
        for (int r = 0; r < 4; ++r) {
          const float p = __expf(fmaf(SIGMA_INV, sacc[mt][nt][r], -SIGMA_INV));
          lacc[mt][r] += p;
          // C/D layout: row = q*4+r, col = c
          pl[(mg * 32 + mt * 16 + q * 4 + r) * PSTR + dh * 32 + nt * 16 + c] = f2bf(p);
        }

    // B2 RAW barrier: pl writes + kn ds_reads retired (lgkmcnt only).
    // Deliberately NO vmcnt drain — vfrag + DMA(t+1) stay outstanding.
    __builtin_amdgcn_sched_barrier(0);
    asm volatile("s_waitcnt lgkmcnt(0)" ::: "memory");
    __builtin_amdgcn_sched_barrier(0);
    __builtin_amdgcn_s_barrier();
    __builtin_amdgcn_sched_barrier(0);

    // ---- G2: O[32x128] += P[32x64] . V[64x128] ----
    for (int kk = 0; kk < 2; ++kk) {
      bf16x8 ap0 = *(const bf16x8*)(pl + (mg * 32 + c) * PSTR + kk * 32 + q * 8);
      bf16x8 ap1 = *(const bf16x8*)(pl + (mg * 32 + 16 + c) * PSTR + kk * 32 + q * 8);
      for (int u = 0; u < 8; ++u) {
        oacc[0][u] = __builtin_amdgcn_mfma_f32_16x16x32_bf16(ap0, vfrag[kk][u], oacc[0][u], 0, 0, 0);
        oacc[1][u] = __builtin_amdgcn_mfma_f32_16x16x32_bf16(ap1, vfrag[kk][u], oacc[1][u], 0, 0, 0);
      }
    }
  }

  // epilogue: row sums across the 16 c-lanes, then device atomics
  for (int mt = 0; mt < 2; ++mt)
    for (int r = 0; r < 4; ++r) {
      float s = lacc[mt][r];
      s += __shfl_xor(s, 1); s += __shfl_xor(s, 2);
      s += __shfl_xor(s, 4); s += __shfl_xor(s, 8);
      if (c == 0)
        atomicAdd(&l_part[row0 + mt * 16 + q * 4 + r], s);
    }
  for (int mt = 0; mt < 2; ++mt)
    for (int u = 0; u < 8; ++u)
      for (int r = 0; r < 4; ++r)
        atomicAdd(&out[(size_t)(row0 + mt * 16 + q * 4 + r) * DDIM + dh * 128 + u * 16 + c],
                  oacc[mt][u][r]);
}

// ---------------- K4: divide by row sums ----------------
__global__ __launch_bounds__(256) void finalize_k(float* __restrict__ out,
                                                  const float* __restrict__ l_part) {
  const int row = blockIdx.x, t = threadIdx.x;
  out[(size_t)row * DDIM + t] /= l_part[row];
}

extern "C" void kernel_launch(void* const* d_in, const int* in_sizes, int n_in,
                              void* d_out, int out_size, void* d_ws, size_t ws_size,
                              hipStream_t stream) {
  const float* emb = (const float*)d_in[0];
  float* out = (float*)d_out;
  char* ws = (char*)d_ws;
  // ws layout: embn 4MB | vt 4MB | l_part 32KB
  unsigned short* embn = (unsigned short*)ws;
  unsigned short* vt   = (unsigned short*)(ws + ((size_t)4 << 20));
  float* l_part        = (float*)(ws + ((size_t)8 << 20));

  hipMemsetAsync(out, 0, (size_t)NROWS * DDIM * sizeof(float), stream);
  hipMemsetAsync(l_part, 0, (size_t)NROWS * sizeof(float), stream);

  normalize_k<<<NROWS / 4, 256, 0, stream>>>(emb, embn);
  transpose_k<<<dim3(NROWS / 64, DDIM / 64), 256, 0, stream>>>(emb, vt);
  fused_k<<<(NROWS / BM) * NSPLIT, 256, 0, stream>>>(embn, vt, out, l_part);
  finalize_k<<<NROWS, 256, 0, stream>>>(out, l_part);
}